// Round 20
// baseline (506.051 us; speedup 1.0000x reference)
//
#include <hip/hip_runtime.h>
#include <cstddef>

#define NN 50000      // nodes
#define NE 800000     // edges (without self loops)
#define NG 250        // graphs
#define TT 200        // nodes per graph / LSTM steps
#define DD 128        // feature dim
#define GH 512        // 4*LSTM_H
#define NEG_SLOPE 0.2f
#define NCHUNK 4
#define CLEN 50       // TT / NCHUNK (fallback path)
#define CAP 128       // per-wave LDS edge cache
#define PSTRIDE 136   // lstm part stride (136%32==8 -> <=2-way)
#define CSTRIDE 132   // staged-C stride
#define GRIDM ((NG * TT + 63) / 64)   // 782

typedef __attribute__((ext_vector_type(8))) short bf16x8;
typedef __attribute__((ext_vector_type(4))) float f32x4;

static __device__ __forceinline__ float fsig(float x) { return 1.0f / (1.0f + __expf(-x)); }
static __device__ __forceinline__ float ftanh(float x) {
    float e = __expf(2.0f * x);
    return 1.0f - 2.0f / (e + 1.0f);
}
static __device__ __forceinline__ unsigned short f2bf(float f) {
    unsigned int u = __float_as_uint(f);
    return (unsigned short)((u + 0x7fffu + ((u >> 16) & 1u)) >> 16);
}
static __device__ __forceinline__ float bf2f(unsigned short b) {
    return __uint_as_float(((unsigned int)b) << 16);
}

// async global->LDS, 16B per lane. dst is wave-uniform base; HW writes dst+lane*16.
static __device__ __forceinline__ void gll16(const void* src, void* ldsdst) {
    __builtin_amdgcn_global_load_lds(
        (const __attribute__((address_space(1))) void*)src,
        (__attribute__((address_space(3))) void*)ldsdst, 16, 0, 0);
}

// ------------------------- fused init -------------------------
__global__ void k_init(int* cnt, int* gstart, int n, int ng1) {
    int i = blockIdx.x * 256 + threadIdx.x;
    if (i < n) cnt[i] = 1;
    if (i < ng1) gstart[i] = n;
}

// --- prep: transposes (fp32 + hi/lo split) + Wih hi/lo split ------------------
__global__ __launch_bounds__(256) void k_prep(
    const float* __restrict__ Wgat, float* __restrict__ WgatT,
    unsigned short* __restrict__ wgatT_hi, unsigned short* __restrict__ wgatT_lo,
    const float* __restrict__ Wgcn, float* __restrict__ WgcnT,
    unsigned short* __restrict__ wgcnT_hi, unsigned short* __restrict__ wgcnT_lo,
    const float* __restrict__ Wih, unsigned short* __restrict__ wih_hi,
    unsigned short* __restrict__ wih_lo)
{
    int i = blockIdx.x * 256 + threadIdx.x;   // 0..65535
    if (i < 16384) {
        int b = i >> 7, k = i & 127;
        float v = Wgat[k * DD + b];
        WgatT[i] = v;
        unsigned short hi = f2bf(v);
        wgatT_hi[i] = hi;
        wgatT_lo[i] = f2bf(v - bf2f(hi));
    } else if (i < 32768) {
        int j = i - 16384, b = j >> 7, k = j & 127;
        float v = Wgcn[k * DD + b];
        WgcnT[j] = v;
        unsigned short hi = f2bf(v);
        wgcnT_hi[j] = hi;
        wgcnT_lo[j] = f2bf(v - bf2f(hi));
    }
    float v = Wih[i];
    unsigned short hi = f2bf(v);
    wih_hi[i] = hi;
    wih_lo[i] = f2bf(v - bf2f(hi));
}

// ------------------------- split x into hi/lo -------------------------
__global__ void k_splitx(const float* __restrict__ x, unsigned short* __restrict__ xh,
                         unsigned short* __restrict__ xl, int n) {
    int i = blockIdx.x * 256 + threadIdx.x;
    if (i >= n) return;
    float v = x[i];
    unsigned short hi = f2bf(v);
    xh[i] = hi;
    xl[i] = f2bf(v - bf2f(hi));
}

// ------------------------- vector GEMM (fallback path only) -------------------
__global__ __launch_bounds__(256) void k_gemm(
    const float* __restrict__ A, const float* __restrict__ B, float* __restrict__ C,
    int M, int N, int t0, int clen, int rowsPerGraph,
    const float* __restrict__ bias1, const float* __restrict__ bias2,
    unsigned short* __restrict__ Cbf,
    float* __restrict__ as_out, float* __restrict__ ad_out,
    const float* __restrict__ a_src, const float* __restrict__ a_dst)
{
    __shared__ float4 As[2][1024];
    __shared__ float4 Bs[2][1024];
    const int tid = threadIdx.x;
    const int wv = tid >> 6;
    const int m0 = blockIdx.x * 128, n0 = blockIdx.y * 128;
    const int tr = tid >> 4, tc = tid & 15;

    float acc[8][8];
    #pragma unroll
    for (int i = 0; i < 8; ++i)
        #pragma unroll
        for (int j = 0; j < 8; ++j) acc[i][j] = 0.f;

    auto stageA = [&](int buf, int k0) {
        #pragma unroll
        for (int it = 0; it < 4; ++it) {
            int f4 = it * 256 + tid;
            int r = f4 >> 3;
            int c4s = (f4 & 7) ^ (r & 7);
            int gr = m0 + r;
            float* dst = (float*)&As[buf][it * 256 + wv * 64];
            if (gr < M) {
                int flat = (gr / clen) * rowsPerGraph + t0 + (gr % clen);
                gll16(A + (size_t)flat * DD + k0 + c4s * 4, dst);
            }
        }
    };
    auto stageB = [&](int buf, int k0) {
        #pragma unroll
        for (int it = 0; it < 4; ++it) {
            int f4 = it * 256 + tid;
            int r = f4 >> 3;
            int c4s = (f4 & 7) ^ (r & 7);
            int gn = n0 + r;
            float* dst = (float*)&Bs[buf][it * 256 + wv * 64];
            if (gn < N) gll16(B + (size_t)gn * DD + k0 + c4s * 4, dst);
        }
    };

    stageA(0, 0); stageB(0, 0);
    __syncthreads();
    int buf = 0;
    const int axor = tr & 7;
    const int bxor = tc & 7;
    for (int ks = 0; ks < 4; ++ks) {
        if (ks < 3) { stageA(buf ^ 1, (ks + 1) * 32); stageB(buf ^ 1, (ks + 1) * 32); }
        const float4* Af = &As[buf][0];
        const float4* Bf = &Bs[buf][0];
        #pragma unroll 1
        for (int k4 = 0; k4 < 8; ++k4) {
            float4 a[8], b[8];
            #pragma unroll
            for (int i = 0; i < 8; ++i) a[i] = Af[(tr + i * 16) * 8 + (k4 ^ axor)];
            #pragma unroll
            for (int j = 0; j < 8; ++j) b[j] = Bf[(tc + j * 16) * 8 + (k4 ^ bxor)];
            #pragma unroll
            for (int i = 0; i < 8; ++i)
                #pragma unroll
                for (int j = 0; j < 8; ++j)
                    acc[i][j] += a[i].x * b[j].x + a[i].y * b[j].y + a[i].z * b[j].z + a[i].w * b[j].w;
        }
        __syncthreads();
        buf ^= 1;
    }

    if (as_out) {
        float asv[8], adv[8];
        #pragma unroll
        for (int j = 0; j < 8; ++j) { asv[j] = a_src[tc + 16 * j]; adv[j] = a_dst[tc + 16 * j]; }
        #pragma unroll
        for (int i = 0; i < 8; ++i) {
            float s = 0.f, d = 0.f;
            #pragma unroll
            for (int j = 0; j < 8; ++j) { s += acc[i][j] * asv[j]; d += acc[i][j] * adv[j]; }
            #pragma unroll
            for (int off = 1; off < 16; off <<= 1) { s += __shfl_xor(s, off); d += __shfl_xor(d, off); }
            int gr = m0 + tr + i * 16;
            if (tc == 0 && gr < M) { as_out[gr] = s; ad_out[gr] = d; }
        }
    }

    #pragma unroll
    for (int i = 0; i < 8; ++i) {
        int gr = m0 + tr + i * 16;
        if (gr >= M) continue;
        #pragma unroll
        for (int j = 0; j < 8; ++j) {
            int gn = n0 + tc + j * 16;
            if (gn >= N) continue;
            float v = acc[i][j];
            if (bias1) v += bias1[gn];
            if (bias2) v += bias2[gn];
            if (Cbf) Cbf[(size_t)gr * N + gn] = f2bf(v);
            else     C[(size_t)gr * N + gn] = v;
        }
    }
}

// ------------- MFMA GEMM v4 (xw): pre-split inputs, grid (GRIDM, 4) -------------
__global__ __launch_bounds__(256) void k_gemm_mx(
    const unsigned short* __restrict__ Ahi, const unsigned short* __restrict__ Alo,
    const unsigned short* __restrict__ Bhi, const unsigned short* __restrict__ Blo,
    float* __restrict__ C, int M,
    const float* __restrict__ bias1, const float* __restrict__ bias2)
{
    __shared__ unsigned short AsH[64 * 128];   // 16 KB
    __shared__ unsigned short AsL[64 * 128];   // 16 KB
    __shared__ float Cs[64 * CSTRIDE];         // 33.8 KB
    const int tid = threadIdx.x;
    const int wv = tid >> 6;
    const int l = tid & 63;
    const int m0 = blockIdx.x * 64;
    const int n0 = blockIdx.y * 128;
    const int wr = (wv >> 1) * 32, wc = (wv & 1) * 64;
    const int lr = l & 15, kg = l >> 4;

    #pragma unroll
    for (int it = 0; it < 4; ++it) {
        int f = it * 256 + tid;
        int r = f >> 4, c8 = f & 15;
        int c8s = c8 ^ (r & 15);
        int gr = m0 + r;
        unsigned short* dstH = &AsH[(it * 256 + wv * 64) * 8];
        unsigned short* dstL = &AsL[(it * 256 + wv * 64) * 8];
        if (gr < M) {
            gll16(Ahi + (size_t)gr * DD + c8s * 8, dstH);
            gll16(Alo + (size_t)gr * DD + c8s * 8, dstL);
        }
    }
    __syncthreads();

    f32x4 acc[2][4];
    #pragma unroll
    for (int rt = 0; rt < 2; ++rt)
        #pragma unroll
        for (int ct = 0; ct < 4; ++ct) acc[rt][ct] = (f32x4){0.f, 0.f, 0.f, 0.f};

    #pragma unroll 1
    for (int ks = 0; ks < 4; ++ks) {
        const int qc = ks * 4 + kg;
        bf16x8 bhi[4], blo[4];
        #pragma unroll
        for (int ct = 0; ct < 4; ++ct) {
            size_t boff = (size_t)(n0 + wc + ct * 16 + lr) * DD + qc * 8;
            bhi[ct] = *(const bf16x8*)(Bhi + boff);
            blo[ct] = *(const bf16x8*)(Blo + boff);
        }
        bf16x8 ahi[2], alo[2];
        #pragma unroll
        for (int rt = 0; rt < 2; ++rt) {
            int row = wr + rt * 16 + lr;
            int slot = row * 16 + (qc ^ (row & 15));
            ahi[rt] = *(const bf16x8*)(&AsH[slot * 8]);
            alo[rt] = *(const bf16x8*)(&AsL[slot * 8]);
        }
        #pragma unroll
        for (int rt = 0; rt < 2; ++rt)
            #pragma unroll
            for (int ct = 0; ct < 4; ++ct) {
                acc[rt][ct] = __builtin_amdgcn_mfma_f32_16x16x32_bf16(ahi[rt], bhi[ct], acc[rt][ct], 0, 0, 0);
                acc[rt][ct] = __builtin_amdgcn_mfma_f32_16x16x32_bf16(alo[rt], bhi[ct], acc[rt][ct], 0, 0, 0);
                acc[rt][ct] = __builtin_amdgcn_mfma_f32_16x16x32_bf16(ahi[rt], blo[ct], acc[rt][ct], 0, 0, 0);
            }
    }

    #pragma unroll
    for (int ct = 0; ct < 4; ++ct) {
        int col = wc + ct * 16 + lr;
        float bsum = bias1[n0 + col] + bias2[n0 + col];
        #pragma unroll
        for (int rt = 0; rt < 2; ++rt) {
            int row = wr + rt * 16 + kg * 4;
            #pragma unroll
            for (int r = 0; r < 4; ++r)
                Cs[(row + r) * CSTRIDE + col] = acc[rt][ct][r] + bsum;
        }
    }
    __syncthreads();
    #pragma unroll
    for (int it = 0; it < 8; ++it) {
        int f4 = it * 256 + tid;
        int r = f4 >> 5, c4 = f4 & 31;
        int gr = m0 + r;
        if (gr < M)
            *(float4*)(C + (size_t)gr * GH + n0 + c4 * 4) = *(const float4*)(&Cs[r * CSTRIDE + c4 * 4]);
    }
}

// ---- MFMA GEMM N=128 v2 (h1/h2): FULLY pre-split, bf16 out + fused alpha ------
__global__ __launch_bounds__(256) void k_gemm_mx128(
    const unsigned short* __restrict__ Ahi, const unsigned short* __restrict__ Alo,
    const unsigned short* __restrict__ Bhi, const unsigned short* __restrict__ Blo,
    unsigned short* __restrict__ Cbf, int M,
    float* __restrict__ as_out, float* __restrict__ ad_out,
    const float* __restrict__ a_src, const float* __restrict__ a_dst)
{
    __shared__ unsigned short AsH[128 * 128];   // 32 KB
    __shared__ unsigned short AsL[128 * 128];   // 32 KB
    const int tid = threadIdx.x;
    const int wv = tid >> 6;
    const int l = tid & 63;
    const int lr = l & 15, kg = l >> 4;
    const int m0 = blockIdx.x * 128;
    const int rowbase = wv * 32;

    #pragma unroll
    for (int it = 0; it < 8; ++it) {
        int f = it * 256 + tid;
        int r = f >> 4, c8 = f & 15;
        int c8s = c8 ^ (r & 15);
        int gr = m0 + r;
        unsigned short* dstH = &AsH[(it * 256 + wv * 64) * 8];
        unsigned short* dstL = &AsL[(it * 256 + wv * 64) * 8];
        if (gr < M) {
            gll16(Ahi + (size_t)gr * DD + c8s * 8, dstH);
            gll16(Alo + (size_t)gr * DD + c8s * 8, dstL);
        }
    }
    __syncthreads();

    f32x4 acc[2][8];
    #pragma unroll
    for (int rt = 0; rt < 2; ++rt)
        #pragma unroll
        for (int ct = 0; ct < 8; ++ct) acc[rt][ct] = (f32x4){0.f, 0.f, 0.f, 0.f};

    #pragma unroll 1
    for (int ks = 0; ks < 4; ++ks) {
        const int qc = ks * 4 + kg;
        bf16x8 bhi[8], blo[8];
        #pragma unroll
        for (int ct = 0; ct < 8; ++ct) {
            size_t boff = (size_t)(ct * 16 + lr) * DD + qc * 8;
            bhi[ct] = *(const bf16x8*)(Bhi + boff);
            blo[ct] = *(const bf16x8*)(Blo + boff);
        }
        bf16x8 ahi[2], alo[2];
        #pragma unroll
        for (int rt = 0; rt < 2; ++rt) {
            int row = rowbase + rt * 16 + lr;
            int slot = row * 16 + (qc ^ (row & 15));
            ahi[rt] = *(const bf16x8*)(&AsH[slot * 8]);
            alo[rt] = *(const bf16x8*)(&AsL[slot * 8]);
        }
        #pragma unroll
        for (int rt = 0; rt < 2; ++rt)
            #pragma unroll
            for (int ct = 0; ct < 8; ++ct) {
                acc[rt][ct] = __builtin_amdgcn_mfma_f32_16x16x32_bf16(ahi[rt], bhi[ct], acc[rt][ct], 0, 0, 0);
                acc[rt][ct] = __builtin_amdgcn_mfma_f32_16x16x32_bf16(alo[rt], bhi[ct], acc[rt][ct], 0, 0, 0);
                acc[rt][ct] = __builtin_amdgcn_mfma_f32_16x16x32_bf16(ahi[rt], blo[ct], acc[rt][ct], 0, 0, 0);
            }
    }

    #pragma unroll
    for (int rt = 0; rt < 2; ++rt)
        #pragma unroll
        for (int ct = 0; ct < 8; ++ct) {
            int row = m0 + rowbase + rt * 16 + kg * 4;
            int col = ct * 16 + lr;
            #pragma unroll
            for (int r = 0; r < 4; ++r)
                if (row + r < M) Cbf[(size_t)(row + r) * DD + col] = f2bf(acc[rt][ct][r]);
        }
    if (as_out) {
        #pragma unroll
        for (int rt = 0; rt < 2; ++rt)
            #pragma unroll
            for (int r = 0; r < 4; ++r) {
                float s = 0.f, d = 0.f;
                #pragma unroll
                for (int ct = 0; ct < 8; ++ct) {
                    int col = ct * 16 + lr;
                    s += acc[rt][ct][r] * a_src[col];
                    d += acc[rt][ct][r] * a_dst[col];
                }
                #pragma unroll
                for (int off = 1; off < 16; off <<= 1) {
                    s += __shfl_xor(s, off);
                    d += __shfl_xor(d, off);
                }
                int row = m0 + rowbase + rt * 16 + kg * 4 + r;
                if (lr == 0 && row < M) { as_out[row] = s; ad_out[row] = d; }
            }
    }
}

// ------------------------- CSR build -------------------------
__global__ void k_hist(const int* __restrict__ ei, int* cnt, int E) {
    int e = blockIdx.x * 256 + threadIdx.x;
    if (e < E) atomicAdd(&cnt[ei[E + e]], 1);
}

__global__ __launch_bounds__(256) void k_scan1(const int* __restrict__ cnt, int* __restrict__ fill,
                                               int* __restrict__ bsum, int n) {
    __shared__ int wsum[4];
    int tid = threadIdx.x, lane = tid & 63, wv = tid >> 6;
    int i = blockIdx.x * 256 + tid;
    int v = (i < n) ? cnt[i] : 0;
    int sc = v;
    #pragma unroll
    for (int off = 1; off < 64; off <<= 1) {
        int t = __shfl_up(sc, off);
        if (lane >= off) sc += t;
    }
    if (lane == 63) wsum[wv] = sc;
    __syncthreads();
    int base = 0;
    if (wv > 0) base += wsum[0];
    if (wv > 1) base += wsum[1];
    if (wv > 2) base += wsum[2];
    if (i < n) fill[i] = base + sc - v;
    if (tid == 255) bsum[blockIdx.x] = base + sc;
}
__global__ __launch_bounds__(256) void k_scan2(int* __restrict__ bsum, int nb) {
    __shared__ int wsum[4];
    int tid = threadIdx.x, lane = tid & 63, wv = tid >> 6;
    int v = (tid < nb) ? bsum[tid] : 0;
    int sc = v;
    #pragma unroll
    for (int off = 1; off < 64; off <<= 1) {
        int t = __shfl_up(sc, off);
        if (lane >= off) sc += t;
    }
    if (lane == 63) wsum[wv] = sc;
    __syncthreads();
    int base = 0;
    if (wv > 0) base += wsum[0];
    if (wv > 1) base += wsum[1];
    if (wv > 2) base += wsum[2];
    if (tid < nb) bsum[tid] = base + sc - v;
}
__global__ void k_scan3(const int* __restrict__ bsum, const int* __restrict__ cnt,
                        int* __restrict__ rp, int* __restrict__ fill,
                        float* __restrict__ dinv, const int* __restrict__ batch,
                        int* __restrict__ gstart, int n) {
    int i = blockIdx.x * 256 + threadIdx.x;
    if (i >= n) return;
    int v = fill[i] + bsum[blockIdx.x];
    rp[i] = v;
    fill[i] = v;
    if (i == n - 1) rp[n] = v + cnt[i];
    dinv[i] = rsqrtf(fmaxf((float)cnt[i], 1.0f));
    int b = batch[i];
    if (i == 0 || batch[i - 1] != b) gstart[b] = i;
}

__global__ void k_fill(const int* __restrict__ ei, int* fill, int* esrc, int E, int N) {
    int i = blockIdx.x * 256 + threadIdx.x;
    if (i < E) {
        int s = ei[i], d = ei[E + i];
        int slot = atomicAdd(&fill[d], 1);
        esrc[slot] = s;
    } else if (i < E + N) {
        int v = i - E;
        int slot = atomicAdd(&fill[v], 1);
        esrc[slot] = v;
    }
}

// -------- GAT aggregation (bf16 gather) -> gato (fp32 OR hi/lo split) ----------
__global__ __launch_bounds__(256) void k_gat(
    const unsigned int* __restrict__ h1b,
    const float* __restrict__ as, const float* __restrict__ ad_,
    const int* __restrict__ rp, const int* __restrict__ esrc,
    const float* __restrict__ bias, float* __restrict__ out,
    unsigned short* __restrict__ oh, unsigned short* __restrict__ ol, int n)
{
    __shared__ float2 ws_sh[4][CAP];
    int wv = threadIdx.x >> 6;
    int node = blockIdx.x * 4 + wv;
    int lane = threadIdx.x & 63;
    if (node >= n) return;
    int r0 = rp[node], r1 = rp[node + 1];
    int deg = r1 - r0;
    float adv = ad_[node];

    float sum = 0.f;
    for (int base = 0; base < deg; base += 64) {
        int idx = base + lane;
        float ex = 0.f;
        if (idx < deg) {
            int s = esrc[r0 + idx];
            float e = as[s] + adv;
            e = e > 0.f ? e : NEG_SLOPE * e;
            ex = __expf(e);
            if (idx < CAP) ws_sh[wv][idx] = make_float2(ex, __int_as_float(s));
        }
        sum += ex;
    }
    #pragma unroll
    for (int off = 1; off < 64; off <<= 1) sum += __shfl_xor(sum, off);
    float inv = 1.0f / sum;

    int nser = deg < CAP ? deg : CAP;
    int npad = (nser + 7) & ~7;
    for (int p = nser + lane; p < npad; p += 64)
        ws_sh[wv][p] = make_float2(0.f, __int_as_float(0));

    float ax = 0.f, ay = 0.f;
    float wa[8]; unsigned int va[8];
    #pragma unroll
    for (int u = 0; u < 8; ++u) {
        float2 t = ws_sh[wv][u];
        wa[u] = t.x; va[u] = h1b[(size_t)__float_as_int(t.y) * 64 + lane];
    }
    #pragma unroll 1
    for (int idx = 8; idx < npad; idx += 8) {
        float wb[8]; unsigned int vb[8];
        #pragma unroll
        for (int u = 0; u < 8; ++u) {
            float2 t = ws_sh[wv][idx + u];
            wb[u] = t.x; vb[u] = h1b[(size_t)__float_as_int(t.y) * 64 + lane];
        }
        #pragma unroll
        for (int u = 0; u < 8; ++u) {
            ax += wa[u] * __uint_as_float(va[u] << 16);
            ay += wa[u] * __uint_as_float(va[u] & 0xffff0000u);
        }
        #pragma unroll
        for (int u = 0; u < 8; ++u) { wa[u] = wb[u]; va[u] = vb[u]; }
    }
    #pragma unroll
    for (int u = 0; u < 8; ++u) {
        ax += wa[u] * __uint_as_float(va[u] << 16);
        ay += wa[u] * __uint_as_float(va[u] & 0xffff0000u);
    }

    for (int j = r0 + CAP; j < r1; ++j) {
        int s = esrc[j];
        float e = as[s] + adv;
        e = e > 0.f ? e : NEG_SLOPE * e;
        float w = __expf(e);
        unsigned int v = h1b[(size_t)s * 64 + lane];
        ax += w * __uint_as_float(v << 16);
        ay += w * __uint_as_float(v & 0xffff0000u);
    }
    float2 bv = *(const float2*)(bias + 2 * lane);
    float vx = fmaxf(ax * inv + bv.x, 0.f);
    float vy = fmaxf(ay * inv + bv.y, 0.f);
    if (oh) {
        unsigned short hx = f2bf(vx), hy = f2bf(vy);
        *(ushort2*)(oh + (size_t)node * DD + 2 * lane) = make_ushort2(hx, hy);
        *(ushort2*)(ol + (size_t)node * DD + 2 * lane) =
            make_ushort2(f2bf(vx - bf2f(hx)), f2bf(vy - bf2f(hy)));
    } else {
        *(float2*)(out + (size_t)node * DD + 2 * lane) = make_float2(vx, vy);
    }
}

// ------------- GCN aggregation (bf16 gather) -> padded (fp32 OR hi/lo split) ----
__global__ __launch_bounds__(256) void k_gcn(
    const unsigned int* __restrict__ h2b, const float* __restrict__ dinv,
    const int* __restrict__ rp, const int* __restrict__ esrc,
    const float* __restrict__ bias, const int* __restrict__ batch,
    const int* __restrict__ gstart, float* __restrict__ padded,
    unsigned short* __restrict__ ph, unsigned short* __restrict__ pl, int n)
{
    __shared__ float2 cs_sh[4][CAP];
    int wv = threadIdx.x >> 6;
    int node = blockIdx.x * 4 + wv;
    int lane = threadIdx.x & 63;
    if (node >= n) return;
    int r0 = rp[node], r1 = rp[node + 1];
    int deg = r1 - r0;
    float dn = dinv[node];

    for (int base = 0; base < deg; base += 64) {
        int idx = base + lane;
        if (idx < deg && idx < CAP) {
            int s = esrc[r0 + idx];
            cs_sh[wv][idx] = make_float2(dinv[s], __int_as_float(s));
        }
    }
    int nser = deg < CAP ? deg : CAP;
    int npad = (nser + 7) & ~7;
    for (int p = nser + lane; p < npad; p += 64)
        cs_sh[wv][p] = make_float2(0.f, __int_as_float(0));
    __syncthreads();

    float ax = 0.f, ay = 0.f;
    float wa[8]; unsigned int va[8];
    #pragma unroll
    for (int u = 0; u < 8; ++u) {
        float2 t = cs_sh[wv][u];
        wa[u] = t.x; va[u] = h2b[(size_t)__float_as_int(t.y) * 64 + lane];
    }
    #pragma unroll 1
    for (int idx = 8; idx < npad; idx += 8) {
        float wb[8]; unsigned int vb[8];
        #pragma unroll
        for (int u = 0; u < 8; ++u) {
            float2 t = cs_sh[wv][idx + u];
            wb[u] = t.x; vb[u] = h2b[(size_t)__float_as_int(t.y) * 64 + lane];
        }
        #pragma unroll
        for (int u = 0; u < 8; ++u) {
            ax += wa[u] * __uint_as_float(va[u] << 16);
            ay += wa[u] * __uint_as_float(va[u] & 0xffff0000u);
        }
        #pragma unroll
        for (int u = 0; u < 8; ++u) { wa[u] = wb[u]; va[u] = vb[u]; }
    }
    #pragma unroll
    for (int u = 0; u < 8; ++u) {
        ax += wa[u] * __uint_as_float(va[u] << 16);
        ay += wa[u] * __uint_as_float(va[u] & 0xffff0000u);
    }

    for (int j = r0 + CAP; j < r1; ++j) {
        int s = esrc[j];
        float c = dinv[s];
        unsigned int v = h2b[(size_t)s * 64 + lane];
        ax += c * __uint_as_float(v << 16);
        ay += c * __uint_as_float(v & 0xffff0000u);
    }
    int g = batch[node];
    if (g < 0 || g >= NG) return;
    int p = node - gstart[g];
    if (p < 0 || p >= TT) return;
    float2 bv = *(const float2*)(bias + 2 * lane);
    float vx = fmaxf(ax * dn + bv.x, 0.f);
    float vy = fmaxf(ay * dn + bv.y, 0.f);
    size_t row = (size_t)g * TT + p;
    if (ph) {
        unsigned short hx = f2bf(vx), hy = f2bf(vy);
        *(ushort2*)(ph + row * DD + 2 * lane) = make_ushort2(hx, hy);
        *(ushort2*)(pl + row * DD + 2 * lane) =
            make_ushort2(f2bf(vx - bf2f(hx)), f2bf(vy - bf2f(hy)));
    } else {
        *(float2*)(padded + row * DD + 2 * lane) = make_float2(vx, vy);
    }
}

// ---- LSTM (512 thr, 4-way split-K). launch_bounds(512,2) + inline-asm keep-alive
// pins the 128-VGPR weight array: asm makes each value opaque so the compiler
// CANNOT rematerialize it from Whh (r17-r18: VGPR=100 => weights re-fetched from
// L1 every step, ~4x the algorithmic VALU issue).
__global__ __launch_bounds__(512, 2) void k_lstm(
    const float* __restrict__ xw, const float* __restrict__ Whh,
    const int* __restrict__ gstart,
    float* __restrict__ hstate, float* __restrict__ cstate,
    float* __restrict__ grep, int t0, int clen)
{
    int g = blockIdx.x, tid = threadIdx.x;
    __shared__ __align__(16) float h_sh[DD];
    __shared__ __align__(16) float part[4][4 * PSTRIDE];

    const int seg = tid >> 7;
    const int gq  = tid & 127;
    const int qt  = gq >> 5;
    const int ub  = (gq & 31) * 4;
    const int u   = tid >> 2;
    const int q   = tid & 3;
    const int lane = tid & 63;
    const int qbase = lane & ~3;

    float4 w[4][8];
    #pragma unroll
    for (int g4 = 0; g4 < 4; ++g4)
        #pragma unroll
        for (int i = 0; i < 8; ++i) {
            w[g4][i] = *(const float4*)(Whh + (size_t)(4 * gq + g4) * DD + seg * 32 + i * 4);
            // opaque keep-alive: forbids rematerialization from memory
            asm volatile("" : "+v"(w[g4][i].x), "+v"(w[g4][i].y),
                              "+v"(w[g4][i].z), "+v"(w[g4][i].w));
        }

    float creg = 0.f, hn = 0.f;
    if (t0 == 0) {
        if (tid < DD) h_sh[tid] = 0.f;
    } else {
        creg = cstate[g * DD + u];
        hn = hstate[g * DD + u];
        if (q == 0) h_sh[u] = hn;
    }
    int take = gstart[g + 1] - gstart[g] - 1;
    if (take < 0) take = 0;
    if (take > TT - 1) take = TT - 1;
    __syncthreads();

    const float* xb = xw + (size_t)g * clen * GH + q * DD + u;
    float xv = xb[0];

    for (int t = t0; t < t0 + clen; ++t) {
        int rel = t - t0;
        float xvn = 0.f;
        if (rel + 1 < clen) xvn = xb[(size_t)(rel + 1) * GH];

        float4 hseg[8];
        #pragma unroll
        for (int i = 0; i < 8; ++i) hseg[i] = *(const float4*)(h_sh + seg * 32 + i * 4);
        float p0 = 0.f, p1 = 0.f, p2 = 0.f, p3 = 0.f;
        #pragma unroll
        for (int i = 0; i < 8; ++i) {
            float4 h4 = hseg[i];
            p0 += h4.x * w[0][i].x + h4.y * w[0][i].y + h4.z * w[0][i].z + h4.w * w[0][i].w;
            p1 += h4.x * w[1][i].x + h4.y * w[1][i].y + h4.z * w[1][i].z + h4.w * w[1][i].w;
            p2 += h4.x * w[2][i].x + h4.y * w[2][i].y + h4.z * w[2][i].z + h4.w * w[2][i].w;
            p3 += h4.x * w[3][i].x + h4.y * w[3][i].y + h4.z * w[3][i].z + h4.w * w[3][i].w;
        }
        *(float4*)(&part[seg][qt * PSTRIDE + ub]) = make_float4(p0, p1, p2, p3);
        __syncthreads();

        int pidx = q * PSTRIDE + u;
        float G = xv + part[0][pidx] + part[1][pidx] + part[2][pidx] + part[3][pidx];
        float a = (q == 2) ? 2.f : -1.f;
        float e = __expf(a * G);
        float act = (q == 2) ? (1.f - 2.f / (e + 1.f)) : (1.f / (1.f + e));
        float ai = __shfl(act, qbase + 0);
        float af = __shfl(act, qbase + 1);
        float ag = __shfl(act, qbase + 2);
        float ao = __shfl(act, qbase + 3);
        creg = af * creg + ai * ag;
        hn = ao * ftanh(creg);
        if (q == 0) {
            h_sh[u] = hn;
            if (t == take) grep[g * DD + u] = hn;
        }
        xv = xvn;
        __syncthreads();
    }
    if (q == 0) { hstate[g * DD + u] = hn; cstate[g * DD + u] = creg; }
}

// ------------------------- FC -------------------------
__global__ void k_fc(const float* __restrict__ grep, const float* __restrict__ Wfc,
                     const float* __restrict__ bfc, float* __restrict__ out, int G) {
    int i = blockIdx.x * 256 + threadIdx.x;
    if (i >= G * 2) return;
    int g = i >> 1, o = i & 1;
    float acc = bfc[o];
    for (int d = 0; d < DD; ++d) acc += grep[g * DD + d] * Wfc[d * 2 + o];
    out[i] = acc;
}

// ------------------------- host launch -------------------------
extern "C" void kernel_launch(void* const* d_in, const int* in_sizes, int n_in,
                              void* d_out, int out_size, void* d_ws, size_t ws_size,
                              hipStream_t stream) {
    const float* x     = (const float*)d_in[0];
    const int*   ei    = (const int*)d_in[1];
    const int*   batch = (const int*)d_in[2];
    const float* Wgat  = (const float*)d_in[3];
    const float* a_src = (const float*)d_in[4];
    const float* a_dst = (const float*)d_in[5];
    const float* b_gat = (const float*)d_in[6];
    const float* Wgcn  = (const float*)d_in[7];
    const float* b_gcn = (const float*)d_in[8];
    const float* Wih   = (const float*)d_in[9];   // [512,128]
    const float* Whh   = (const float*)d_in[10];  // [512,128]
    const float* b_ih  = (const float*)d_in[11];
    const float* b_hh  = (const float*)d_in[12];
    const float* Wfc   = (const float*)d_in[13];
    const float* b_fc  = (const float*)d_in[14];
    float* out = (float*)d_out;

    float* ws = (float*)d_ws;
    const size_t F = (size_t)NN * DD;  // 6.4M elements
    unsigned short* h1b = (unsigned short*)ws;
    unsigned short* h2b = (unsigned short*)ws;
    float* xwChunk = ws;
    float* gato   = ws + F;
    float* padded = ws + F;
    unsigned short* gato_hi = (unsigned short*)(ws + F);
    unsigned short* gato_lo = gato_hi + F;
    unsigned short* padded_hi = (unsigned short*)(ws + F);
    unsigned short* padded_lo = padded_hi + F;
    size_t off = 2 * F;
    float* alpha_s = ws + off; off += 50048;
    float* alpha_d = ws + off; off += 50048;
    float* dinv    = ws + off; off += 50048;
    int*   cnt     = (int*)(ws + off); off += 50048;
    int*   rp      = (int*)(ws + off); off += 50056;
    int*   fill    = (int*)(ws + off); off += 50048;
    int*   esrc    = (int*)(ws + off); off += 850048;
    int*   bsum    = (int*)(ws + off); off += 256;
    int*   gstart  = (int*)(ws + off); off += 256;
    float* grep    = ws + off; off += 32000;
    float* hstate  = ws + off; off += 32000;
    float* cstate  = ws + off; off += 32000;
    float* WgatT   = ws + off; off += 16384;
    float* WgcnT   = ws + off; off += 16384;
    unsigned short* wih_hi = (unsigned short*)(ws + off); off += 32768;
    unsigned short* wih_lo = (unsigned short*)(ws + off); off += 32768;
    unsigned short* wgatT_hi = (unsigned short*)(ws + off); off += 8192;
    unsigned short* wgatT_lo = (unsigned short*)(ws + off); off += 8192;
    unsigned short* wgcnT_hi = (unsigned short*)(ws + off); off += 8192;
    unsigned short* wgcnT_lo = (unsigned short*)(ws + off); off += 8192;
    unsigned short* x_hi = (unsigned short*)(ws + off); off += F / 2;
    unsigned short* x_lo = (unsigned short*)(ws + off); off += F / 2;
    const size_t xwBigFloats = (size_t)NG * TT * GH;   // 25.6M floats
    float* xwBig = ws + off;
    const bool big = ws_size >= (off + xwBigFloats) * sizeof(float);

    // 1. prep: transposes + all weight hi/lo splits
    k_prep<<<256, 256, 0, stream>>>(Wgat, WgatT, wgatT_hi, wgatT_lo,
                                    Wgcn, WgcnT, wgcnT_hi, wgcnT_lo,
                                    Wih, wih_hi, wih_lo);

    // 2. h1b = bf16(x @ W_gat), alpha fused
    if (big) {
        k_splitx<<<25000, 256, 0, stream>>>(x, x_hi, x_lo, (int)F);
        k_gemm_mx128<<<391, 256, 0, stream>>>(x_hi, x_lo, wgatT_hi, wgatT_lo, h1b, NN,
                                              alpha_s, alpha_d, a_src, a_dst);
    } else {
        k_gemm<<<dim3(391, 1), 256, 0, stream>>>(x, WgatT, nullptr, NN, DD, 0, TT, TT,
                                                 nullptr, nullptr, h1b,
                                                 alpha_s, alpha_d, a_src, a_dst);
    }

    // 3. CSR build
    k_init<<<196, 256, 0, stream>>>(cnt, gstart, NN, NG + 1);
    k_hist<<<3125, 256, 0, stream>>>(ei, cnt, NE);
    k_scan1<<<196, 256, 0, stream>>>(cnt, fill, bsum, NN);
    k_scan2<<<1, 256, 0, stream>>>(bsum, 196);
    k_scan3<<<196, 256, 0, stream>>>(bsum, cnt, rp, fill, dinv, batch, gstart, NN);
    k_fill<<<3321, 256, 0, stream>>>(ei, fill, esrc, NE, NN);

    // 4. GAT aggregation -> gato (hi/lo when big)
    if (big) {
        k_gat<<<12500, 256, 0, stream>>>((const unsigned int*)h1b, alpha_s, alpha_d,
                                         rp, esrc, b_gat, nullptr, gato_hi, gato_lo, NN);
    } else {
        k_gat<<<12500, 256, 0, stream>>>((const unsigned int*)h1b, alpha_s, alpha_d,
                                         rp, esrc, b_gat, gato, nullptr, nullptr, NN);
    }

    // 5. h2b = bf16(gato @ W_gcn)
    if (big) {
        k_gemm_mx128<<<391, 256, 0, stream>>>(gato_hi, gato_lo, wgcnT_hi, wgcnT_lo, h2b, NN,
                                              nullptr, nullptr, nullptr, nullptr);
    } else {
        k_gemm<<<dim3(391, 1), 256, 0, stream>>>(gato, WgcnT, nullptr, NN, DD, 0, TT, TT,
                                                 nullptr, nullptr, h2b,
                                                 nullptr, nullptr, nullptr, nullptr);
    }

    // 6. GCN aggregation -> padded (hi/lo when big)
    if (big) {
        k_gcn<<<12500, 256, 0, stream>>>((const unsigned int*)h2b, dinv, rp, esrc,
                                         b_gcn, batch, gstart, nullptr,
                                         padded_hi, padded_lo, NN);
    } else {
        k_gcn<<<12500, 256, 0, stream>>>((const unsigned int*)h2b, dinv, rp, esrc,
                                         b_gcn, batch, gstart, padded,
                                         nullptr, nullptr, NN);
    }

    // 7. LSTM: conversion-free MFMA xw gemm + pinned-weight recurrence
    if (big) {
        k_gemm_mx<<<dim3(GRIDM, 4), 256, 0, stream>>>(padded_hi, padded_lo,
                                                      wih_hi, wih_lo,
                                                      xwBig, NG * TT, b_ih, b_hh);
        k_lstm<<<NG, 512, 0, stream>>>(xwBig, Whh, gstart, hstate, cstate, grep, 0, TT);
    } else {
        for (int c = 0; c < NCHUNK; ++c) {
            int t0 = c * CLEN;
            k_gemm<<<dim3(98, 4), 256, 0, stream>>>(padded, Wih, xwChunk, NG * CLEN, GH,
                                                    t0, CLEN, TT, b_ih, b_hh,
                                                    nullptr, nullptr, nullptr, nullptr, nullptr);
            k_lstm<<<NG, 512, 0, stream>>>(xwChunk, Whh, gstart, hstate, cstate, grep, t0, CLEN);
        }
    }

    // 8. FC
    k_fc<<<2, 256, 0, stream>>>(grep, Wfc, b_fc, out, NG);
}

// Round 21
// 484.164 us; speedup vs baseline: 1.0452x; 1.0452x over previous
//
#include <hip/hip_runtime.h>
#include <cstddef>

#define NN 50000      // nodes
#define NE 800000     // edges (without self loops)
#define NG 250        // graphs
#define TT 200        // nodes per graph / LSTM steps
#define DD 128        // feature dim
#define GH 512        // 4*LSTM_H
#define NEG_SLOPE 0.2f
#define NCHUNK 4
#define CLEN 50       // TT / NCHUNK (fallback path)
#define CAP 128       // per-wave LDS edge cache
#define PSTRIDE 136   // lstm part stride (136%32==8 -> <=2-way)
#define CSTRIDE 132   // staged-C stride
#define GRIDM ((NG * TT + 63) / 64)   // 782

typedef __attribute__((ext_vector_type(8))) short bf16x8;
typedef __attribute__((ext_vector_type(4))) float f32x4;

static __device__ __forceinline__ float fsig(float x) { return 1.0f / (1.0f + __expf(-x)); }
static __device__ __forceinline__ float ftanh(float x) {
    float e = __expf(2.0f * x);
    return 1.0f - 2.0f / (e + 1.0f);
}
static __device__ __forceinline__ unsigned short f2bf(float f) {
    unsigned int u = __float_as_uint(f);
    return (unsigned short)((u + 0x7fffu + ((u >> 16) & 1u)) >> 16);
}
static __device__ __forceinline__ float bf2f(unsigned short b) {
    return __uint_as_float(((unsigned int)b) << 16);
}

// async global->LDS, 16B per lane. dst is wave-uniform base; HW writes dst+lane*16.
static __device__ __forceinline__ void gll16(const void* src, void* ldsdst) {
    __builtin_amdgcn_global_load_lds(
        (const __attribute__((address_space(1))) void*)src,
        (__attribute__((address_space(3))) void*)ldsdst, 16, 0, 0);
}

// ------------------------- fused init -------------------------
__global__ void k_init(int* cnt, int* gstart, int n, int ng1) {
    int i = blockIdx.x * 256 + threadIdx.x;
    if (i < n) cnt[i] = 1;
    if (i < ng1) gstart[i] = n;
}

// --- prep: transposes (fp32 + hi/lo split) + Wih hi/lo split ------------------
__global__ __launch_bounds__(256) void k_prep(
    const float* __restrict__ Wgat, float* __restrict__ WgatT,
    unsigned short* __restrict__ wgatT_hi, unsigned short* __restrict__ wgatT_lo,
    const float* __restrict__ Wgcn, float* __restrict__ WgcnT,
    unsigned short* __restrict__ wgcnT_hi, unsigned short* __restrict__ wgcnT_lo,
    const float* __restrict__ Wih, unsigned short* __restrict__ wih_hi,
    unsigned short* __restrict__ wih_lo)
{
    int i = blockIdx.x * 256 + threadIdx.x;   // 0..65535
    if (i < 16384) {
        int b = i >> 7, k = i & 127;
        float v = Wgat[k * DD + b];
        WgatT[i] = v;
        unsigned short hi = f2bf(v);
        wgatT_hi[i] = hi;
        wgatT_lo[i] = f2bf(v - bf2f(hi));
    } else if (i < 32768) {
        int j = i - 16384, b = j >> 7, k = j & 127;
        float v = Wgcn[k * DD + b];
        WgcnT[j] = v;
        unsigned short hi = f2bf(v);
        wgcnT_hi[j] = hi;
        wgcnT_lo[j] = f2bf(v - bf2f(hi));
    }
    float v = Wih[i];
    unsigned short hi = f2bf(v);
    wih_hi[i] = hi;
    wih_lo[i] = f2bf(v - bf2f(hi));
}

// ------------------------- split x into hi/lo -------------------------
__global__ void k_splitx(const float* __restrict__ x, unsigned short* __restrict__ xh,
                         unsigned short* __restrict__ xl, int n) {
    int i = blockIdx.x * 256 + threadIdx.x;
    if (i >= n) return;
    float v = x[i];
    unsigned short hi = f2bf(v);
    xh[i] = hi;
    xl[i] = f2bf(v - bf2f(hi));
}

// ------------------------- vector GEMM (fallback path only) -------------------
__global__ __launch_bounds__(256) void k_gemm(
    const float* __restrict__ A, const float* __restrict__ B, float* __restrict__ C,
    int M, int N, int t0, int clen, int rowsPerGraph,
    const float* __restrict__ bias1, const float* __restrict__ bias2,
    unsigned short* __restrict__ Cbf,
    float* __restrict__ as_out, float* __restrict__ ad_out,
    const float* __restrict__ a_src, const float* __restrict__ a_dst)
{
    __shared__ float4 As[2][1024];
    __shared__ float4 Bs[2][1024];
    const int tid = threadIdx.x;
    const int wv = tid >> 6;
    const int m0 = blockIdx.x * 128, n0 = blockIdx.y * 128;
    const int tr = tid >> 4, tc = tid & 15;

    float acc[8][8];
    #pragma unroll
    for (int i = 0; i < 8; ++i)
        #pragma unroll
        for (int j = 0; j < 8; ++j) acc[i][j] = 0.f;

    auto stageA = [&](int buf, int k0) {
        #pragma unroll
        for (int it = 0; it < 4; ++it) {
            int f4 = it * 256 + tid;
            int r = f4 >> 3;
            int c4s = (f4 & 7) ^ (r & 7);
            int gr = m0 + r;
            float* dst = (float*)&As[buf][it * 256 + wv * 64];
            if (gr < M) {
                int flat = (gr / clen) * rowsPerGraph + t0 + (gr % clen);
                gll16(A + (size_t)flat * DD + k0 + c4s * 4, dst);
            }
        }
    };
    auto stageB = [&](int buf, int k0) {
        #pragma unroll
        for (int it = 0; it < 4; ++it) {
            int f4 = it * 256 + tid;
            int r = f4 >> 3;
            int c4s = (f4 & 7) ^ (r & 7);
            int gn = n0 + r;
            float* dst = (float*)&Bs[buf][it * 256 + wv * 64];
            if (gn < N) gll16(B + (size_t)gn * DD + k0 + c4s * 4, dst);
        }
    };

    stageA(0, 0); stageB(0, 0);
    __syncthreads();
    int buf = 0;
    const int axor = tr & 7;
    const int bxor = tc & 7;
    for (int ks = 0; ks < 4; ++ks) {
        if (ks < 3) { stageA(buf ^ 1, (ks + 1) * 32); stageB(buf ^ 1, (ks + 1) * 32); }
        const float4* Af = &As[buf][0];
        const float4* Bf = &Bs[buf][0];
        #pragma unroll 1
        for (int k4 = 0; k4 < 8; ++k4) {
            float4 a[8], b[8];
            #pragma unroll
            for (int i = 0; i < 8; ++i) a[i] = Af[(tr + i * 16) * 8 + (k4 ^ axor)];
            #pragma unroll
            for (int j = 0; j < 8; ++j) b[j] = Bf[(tc + j * 16) * 8 + (k4 ^ bxor)];
            #pragma unroll
            for (int i = 0; i < 8; ++i)
                #pragma unroll
                for (int j = 0; j < 8; ++j)
                    acc[i][j] += a[i].x * b[j].x + a[i].y * b[j].y + a[i].z * b[j].z + a[i].w * b[j].w;
        }
        __syncthreads();
        buf ^= 1;
    }

    if (as_out) {
        float asv[8], adv[8];
        #pragma unroll
        for (int j = 0; j < 8; ++j) { asv[j] = a_src[tc + 16 * j]; adv[j] = a_dst[tc + 16 * j]; }
        #pragma unroll
        for (int i = 0; i < 8; ++i) {
            float s = 0.f, d = 0.f;
            #pragma unroll
            for (int j = 0; j < 8; ++j) { s += acc[i][j] * asv[j]; d += acc[i][j] * adv[j]; }
            #pragma unroll
            for (int off = 1; off < 16; off <<= 1) { s += __shfl_xor(s, off); d += __shfl_xor(d, off); }
            int gr = m0 + tr + i * 16;
            if (tc == 0 && gr < M) { as_out[gr] = s; ad_out[gr] = d; }
        }
    }

    #pragma unroll
    for (int i = 0; i < 8; ++i) {
        int gr = m0 + tr + i * 16;
        if (gr >= M) continue;
        #pragma unroll
        for (int j = 0; j < 8; ++j) {
            int gn = n0 + tc + j * 16;
            if (gn >= N) continue;
            float v = acc[i][j];
            if (bias1) v += bias1[gn];
            if (bias2) v += bias2[gn];
            if (Cbf) Cbf[(size_t)gr * N + gn] = f2bf(v);
            else     C[(size_t)gr * N + gn] = v;
        }
    }
}

// ------------- MFMA GEMM v4 (xw): pre-split inputs, grid (GRIDM, 4) -------------
__global__ __launch_bounds__(256) void k_gemm_mx(
    const unsigned short* __restrict__ Ahi, const unsigned short* __restrict__ Alo,
    const unsigned short* __restrict__ Bhi, const unsigned short* __restrict__ Blo,
    float* __restrict__ C, int M,
    const float* __restrict__ bias1, const float* __restrict__ bias2)
{
    __shared__ unsigned short AsH[64 * 128];   // 16 KB
    __shared__ unsigned short AsL[64 * 128];   // 16 KB
    __shared__ float Cs[64 * CSTRIDE];         // 33.8 KB
    const int tid = threadIdx.x;
    const int wv = tid >> 6;
    const int l = tid & 63;
    const int m0 = blockIdx.x * 64;
    const int n0 = blockIdx.y * 128;
    const int wr = (wv >> 1) * 32, wc = (wv & 1) * 64;
    const int lr = l & 15, kg = l >> 4;

    #pragma unroll
    for (int it = 0; it < 4; ++it) {
        int f = it * 256 + tid;
        int r = f >> 4, c8 = f & 15;
        int c8s = c8 ^ (r & 15);
        int gr = m0 + r;
        unsigned short* dstH = &AsH[(it * 256 + wv * 64) * 8];
        unsigned short* dstL = &AsL[(it * 256 + wv * 64) * 8];
        if (gr < M) {
            gll16(Ahi + (size_t)gr * DD + c8s * 8, dstH);
            gll16(Alo + (size_t)gr * DD + c8s * 8, dstL);
        }
    }
    __syncthreads();

    f32x4 acc[2][4];
    #pragma unroll
    for (int rt = 0; rt < 2; ++rt)
        #pragma unroll
        for (int ct = 0; ct < 4; ++ct) acc[rt][ct] = (f32x4){0.f, 0.f, 0.f, 0.f};

    #pragma unroll 1
    for (int ks = 0; ks < 4; ++ks) {
        const int qc = ks * 4 + kg;
        bf16x8 bhi[4], blo[4];
        #pragma unroll
        for (int ct = 0; ct < 4; ++ct) {
            size_t boff = (size_t)(n0 + wc + ct * 16 + lr) * DD + qc * 8;
            bhi[ct] = *(const bf16x8*)(Bhi + boff);
            blo[ct] = *(const bf16x8*)(Blo + boff);
        }
        bf16x8 ahi[2], alo[2];
        #pragma unroll
        for (int rt = 0; rt < 2; ++rt) {
            int row = wr + rt * 16 + lr;
            int slot = row * 16 + (qc ^ (row & 15));
            ahi[rt] = *(const bf16x8*)(&AsH[slot * 8]);
            alo[rt] = *(const bf16x8*)(&AsL[slot * 8]);
        }
        #pragma unroll
        for (int rt = 0; rt < 2; ++rt)
            #pragma unroll
            for (int ct = 0; ct < 4; ++ct) {
                acc[rt][ct] = __builtin_amdgcn_mfma_f32_16x16x32_bf16(ahi[rt], bhi[ct], acc[rt][ct], 0, 0, 0);
                acc[rt][ct] = __builtin_amdgcn_mfma_f32_16x16x32_bf16(alo[rt], bhi[ct], acc[rt][ct], 0, 0, 0);
                acc[rt][ct] = __builtin_amdgcn_mfma_f32_16x16x32_bf16(ahi[rt], blo[ct], acc[rt][ct], 0, 0, 0);
            }
    }

    #pragma unroll
    for (int ct = 0; ct < 4; ++ct) {
        int col = wc + ct * 16 + lr;
        float bsum = bias1[n0 + col] + bias2[n0 + col];
        #pragma unroll
        for (int rt = 0; rt < 2; ++rt) {
            int row = wr + rt * 16 + kg * 4;
            #pragma unroll
            for (int r = 0; r < 4; ++r)
                Cs[(row + r) * CSTRIDE + col] = acc[rt][ct][r] + bsum;
        }
    }
    __syncthreads();
    #pragma unroll
    for (int it = 0; it < 8; ++it) {
        int f4 = it * 256 + tid;
        int r = f4 >> 5, c4 = f4 & 31;
        int gr = m0 + r;
        if (gr < M)
            *(float4*)(C + (size_t)gr * GH + n0 + c4 * 4) = *(const float4*)(&Cs[r * CSTRIDE + c4 * 4]);
    }
}

// ---- MFMA GEMM N=128 v2 (h1/h2): FULLY pre-split, bf16 out + fused alpha ------
__global__ __launch_bounds__(256) void k_gemm_mx128(
    const unsigned short* __restrict__ Ahi, const unsigned short* __restrict__ Alo,
    const unsigned short* __restrict__ Bhi, const unsigned short* __restrict__ Blo,
    unsigned short* __restrict__ Cbf, int M,
    float* __restrict__ as_out, float* __restrict__ ad_out,
    const float* __restrict__ a_src, const float* __restrict__ a_dst)
{
    __shared__ unsigned short AsH[128 * 128];   // 32 KB
    __shared__ unsigned short AsL[128 * 128];   // 32 KB
    const int tid = threadIdx.x;
    const int wv = tid >> 6;
    const int l = tid & 63;
    const int lr = l & 15, kg = l >> 4;
    const int m0 = blockIdx.x * 128;
    const int rowbase = wv * 32;

    #pragma unroll
    for (int it = 0; it < 8; ++it) {
        int f = it * 256 + tid;
        int r = f >> 4, c8 = f & 15;
        int c8s = c8 ^ (r & 15);
        int gr = m0 + r;
        unsigned short* dstH = &AsH[(it * 256 + wv * 64) * 8];
        unsigned short* dstL = &AsL[(it * 256 + wv * 64) * 8];
        if (gr < M) {
            gll16(Ahi + (size_t)gr * DD + c8s * 8, dstH);
            gll16(Alo + (size_t)gr * DD + c8s * 8, dstL);
        }
    }
    __syncthreads();

    f32x4 acc[2][8];
    #pragma unroll
    for (int rt = 0; rt < 2; ++rt)
        #pragma unroll
        for (int ct = 0; ct < 8; ++ct) acc[rt][ct] = (f32x4){0.f, 0.f, 0.f, 0.f};

    #pragma unroll 1
    for (int ks = 0; ks < 4; ++ks) {
        const int qc = ks * 4 + kg;
        bf16x8 bhi[8], blo[8];
        #pragma unroll
        for (int ct = 0; ct < 8; ++ct) {
            size_t boff = (size_t)(ct * 16 + lr) * DD + qc * 8;
            bhi[ct] = *(const bf16x8*)(Bhi + boff);
            blo[ct] = *(const bf16x8*)(Blo + boff);
        }
        bf16x8 ahi[2], alo[2];
        #pragma unroll
        for (int rt = 0; rt < 2; ++rt) {
            int row = rowbase + rt * 16 + lr;
            int slot = row * 16 + (qc ^ (row & 15));
            ahi[rt] = *(const bf16x8*)(&AsH[slot * 8]);
            alo[rt] = *(const bf16x8*)(&AsL[slot * 8]);
        }
        #pragma unroll
        for (int rt = 0; rt < 2; ++rt)
            #pragma unroll
            for (int ct = 0; ct < 8; ++ct) {
                acc[rt][ct] = __builtin_amdgcn_mfma_f32_16x16x32_bf16(ahi[rt], bhi[ct], acc[rt][ct], 0, 0, 0);
                acc[rt][ct] = __builtin_amdgcn_mfma_f32_16x16x32_bf16(alo[rt], bhi[ct], acc[rt][ct], 0, 0, 0);
                acc[rt][ct] = __builtin_amdgcn_mfma_f32_16x16x32_bf16(ahi[rt], blo[ct], acc[rt][ct], 0, 0, 0);
            }
    }

    #pragma unroll
    for (int rt = 0; rt < 2; ++rt)
        #pragma unroll
        for (int ct = 0; ct < 8; ++ct) {
            int row = m0 + rowbase + rt * 16 + kg * 4;
            int col = ct * 16 + lr;
            #pragma unroll
            for (int r = 0; r < 4; ++r)
                if (row + r < M) Cbf[(size_t)(row + r) * DD + col] = f2bf(acc[rt][ct][r]);
        }
    if (as_out) {
        #pragma unroll
        for (int rt = 0; rt < 2; ++rt)
            #pragma unroll
            for (int r = 0; r < 4; ++r) {
                float s = 0.f, d = 0.f;
                #pragma unroll
                for (int ct = 0; ct < 8; ++ct) {
                    int col = ct * 16 + lr;
                    s += acc[rt][ct][r] * a_src[col];
                    d += acc[rt][ct][r] * a_dst[col];
                }
                #pragma unroll
                for (int off = 1; off < 16; off <<= 1) {
                    s += __shfl_xor(s, off);
                    d += __shfl_xor(d, off);
                }
                int row = m0 + rowbase + rt * 16 + kg * 4 + r;
                if (lr == 0 && row < M) { as_out[row] = s; ad_out[row] = d; }
            }
    }
}

// ------------------------- CSR build -------------------------
__global__ void k_hist(const int* __restrict__ ei, int* cnt, int E) {
    int e = blockIdx.x * 256 + threadIdx.x;
    if (e < E) atomicAdd(&cnt[ei[E + e]], 1);
}

__global__ __launch_bounds__(256) void k_scan1(const int* __restrict__ cnt, int* __restrict__ fill,
                                               int* __restrict__ bsum, int n) {
    __shared__ int wsum[4];
    int tid = threadIdx.x, lane = tid & 63, wv = tid >> 6;
    int i = blockIdx.x * 256 + tid;
    int v = (i < n) ? cnt[i] : 0;
    int sc = v;
    #pragma unroll
    for (int off = 1; off < 64; off <<= 1) {
        int t = __shfl_up(sc, off);
        if (lane >= off) sc += t;
    }
    if (lane == 63) wsum[wv] = sc;
    __syncthreads();
    int base = 0;
    if (wv > 0) base += wsum[0];
    if (wv > 1) base += wsum[1];
    if (wv > 2) base += wsum[2];
    if (i < n) fill[i] = base + sc - v;
    if (tid == 255) bsum[blockIdx.x] = base + sc;
}
__global__ __launch_bounds__(256) void k_scan2(int* __restrict__ bsum, int nb) {
    __shared__ int wsum[4];
    int tid = threadIdx.x, lane = tid & 63, wv = tid >> 6;
    int v = (tid < nb) ? bsum[tid] : 0;
    int sc = v;
    #pragma unroll
    for (int off = 1; off < 64; off <<= 1) {
        int t = __shfl_up(sc, off);
        if (lane >= off) sc += t;
    }
    if (lane == 63) wsum[wv] = sc;
    __syncthreads();
    int base = 0;
    if (wv > 0) base += wsum[0];
    if (wv > 1) base += wsum[1];
    if (wv > 2) base += wsum[2];
    if (tid < nb) bsum[tid] = base + sc - v;
}
__global__ void k_scan3(const int* __restrict__ bsum, const int* __restrict__ cnt,
                        int* __restrict__ rp, int* __restrict__ fill,
                        float* __restrict__ dinv, const int* __restrict__ batch,
                        int* __restrict__ gstart, int n) {
    int i = blockIdx.x * 256 + threadIdx.x;
    if (i >= n) return;
    int v = fill[i] + bsum[blockIdx.x];
    rp[i] = v;
    fill[i] = v;
    if (i == n - 1) rp[n] = v + cnt[i];
    dinv[i] = rsqrtf(fmaxf((float)cnt[i], 1.0f));
    int b = batch[i];
    if (i == 0 || batch[i - 1] != b) gstart[b] = i;
}

__global__ void k_fill(const int* __restrict__ ei, int* fill, int* esrc, int E, int N) {
    int i = blockIdx.x * 256 + threadIdx.x;
    if (i < E) {
        int s = ei[i], d = ei[E + i];
        int slot = atomicAdd(&fill[d], 1);
        esrc[slot] = s;
    } else if (i < E + N) {
        int v = i - E;
        int slot = atomicAdd(&fill[v], 1);
        esrc[slot] = v;
    }
}

// -------- GAT aggregation (bf16 gather) -> gato (fp32 OR hi/lo split) ----------
__global__ __launch_bounds__(256) void k_gat(
    const unsigned int* __restrict__ h1b,
    const float* __restrict__ as, const float* __restrict__ ad_,
    const int* __restrict__ rp, const int* __restrict__ esrc,
    const float* __restrict__ bias, float* __restrict__ out,
    unsigned short* __restrict__ oh, unsigned short* __restrict__ ol, int n)
{
    __shared__ float2 ws_sh[4][CAP];
    int wv = threadIdx.x >> 6;
    int node = blockIdx.x * 4 + wv;
    int lane = threadIdx.x & 63;
    if (node >= n) return;
    int r0 = rp[node], r1 = rp[node + 1];
    int deg = r1 - r0;
    float adv = ad_[node];

    float sum = 0.f;
    for (int base = 0; base < deg; base += 64) {
        int idx = base + lane;
        float ex = 0.f;
        if (idx < deg) {
            int s = esrc[r0 + idx];
            float e = as[s] + adv;
            e = e > 0.f ? e : NEG_SLOPE * e;
            ex = __expf(e);
            if (idx < CAP) ws_sh[wv][idx] = make_float2(ex, __int_as_float(s));
        }
        sum += ex;
    }
    #pragma unroll
    for (int off = 1; off < 64; off <<= 1) sum += __shfl_xor(sum, off);
    float inv = 1.0f / sum;

    int nser = deg < CAP ? deg : CAP;
    int npad = (nser + 7) & ~7;
    for (int p = nser + lane; p < npad; p += 64)
        ws_sh[wv][p] = make_float2(0.f, __int_as_float(0));

    float ax = 0.f, ay = 0.f;
    float wa[8]; unsigned int va[8];
    #pragma unroll
    for (int u = 0; u < 8; ++u) {
        float2 t = ws_sh[wv][u];
        wa[u] = t.x; va[u] = h1b[(size_t)__float_as_int(t.y) * 64 + lane];
    }
    #pragma unroll 1
    for (int idx = 8; idx < npad; idx += 8) {
        float wb[8]; unsigned int vb[8];
        #pragma unroll
        for (int u = 0; u < 8; ++u) {
            float2 t = ws_sh[wv][idx + u];
            wb[u] = t.x; vb[u] = h1b[(size_t)__float_as_int(t.y) * 64 + lane];
        }
        #pragma unroll
        for (int u = 0; u < 8; ++u) {
            ax += wa[u] * __uint_as_float(va[u] << 16);
            ay += wa[u] * __uint_as_float(va[u] & 0xffff0000u);
        }
        #pragma unroll
        for (int u = 0; u < 8; ++u) { wa[u] = wb[u]; va[u] = vb[u]; }
    }
    #pragma unroll
    for (int u = 0; u < 8; ++u) {
        ax += wa[u] * __uint_as_float(va[u] << 16);
        ay += wa[u] * __uint_as_float(va[u] & 0xffff0000u);
    }

    for (int j = r0 + CAP; j < r1; ++j) {
        int s = esrc[j];
        float e = as[s] + adv;
        e = e > 0.f ? e : NEG_SLOPE * e;
        float w = __expf(e);
        unsigned int v = h1b[(size_t)s * 64 + lane];
        ax += w * __uint_as_float(v << 16);
        ay += w * __uint_as_float(v & 0xffff0000u);
    }
    float2 bv = *(const float2*)(bias + 2 * lane);
    float vx = fmaxf(ax * inv + bv.x, 0.f);
    float vy = fmaxf(ay * inv + bv.y, 0.f);
    if (oh) {
        unsigned short hx = f2bf(vx), hy = f2bf(vy);
        *(ushort2*)(oh + (size_t)node * DD + 2 * lane) = make_ushort2(hx, hy);
        *(ushort2*)(ol + (size_t)node * DD + 2 * lane) =
            make_ushort2(f2bf(vx - bf2f(hx)), f2bf(vy - bf2f(hy)));
    } else {
        *(float2*)(out + (size_t)node * DD + 2 * lane) = make_float2(vx, vy);
    }
}

// ------------- GCN aggregation (bf16 gather) -> padded (fp32 OR hi/lo split) ----
__global__ __launch_bounds__(256) void k_gcn(
    const unsigned int* __restrict__ h2b, const float* __restrict__ dinv,
    const int* __restrict__ rp, const int* __restrict__ esrc,
    const float* __restrict__ bias, const int* __restrict__ batch,
    const int* __restrict__ gstart, float* __restrict__ padded,
    unsigned short* __restrict__ ph, unsigned short* __restrict__ pl, int n)
{
    __shared__ float2 cs_sh[4][CAP];
    int wv = threadIdx.x >> 6;
    int node = blockIdx.x * 4 + wv;
    int lane = threadIdx.x & 63;
    if (node >= n) return;
    int r0 = rp[node], r1 = rp[node + 1];
    int deg = r1 - r0;
    float dn = dinv[node];

    for (int base = 0; base < deg; base += 64) {
        int idx = base + lane;
        if (idx < deg && idx < CAP) {
            int s = esrc[r0 + idx];
            cs_sh[wv][idx] = make_float2(dinv[s], __int_as_float(s));
        }
    }
    int nser = deg < CAP ? deg : CAP;
    int npad = (nser + 7) & ~7;
    for (int p = nser + lane; p < npad; p += 64)
        cs_sh[wv][p] = make_float2(0.f, __int_as_float(0));
    __syncthreads();

    float ax = 0.f, ay = 0.f;
    float wa[8]; unsigned int va[8];
    #pragma unroll
    for (int u = 0; u < 8; ++u) {
        float2 t = cs_sh[wv][u];
        wa[u] = t.x; va[u] = h2b[(size_t)__float_as_int(t.y) * 64 + lane];
    }
    #pragma unroll 1
    for (int idx = 8; idx < npad; idx += 8) {
        float wb[8]; unsigned int vb[8];
        #pragma unroll
        for (int u = 0; u < 8; ++u) {
            float2 t = cs_sh[wv][idx + u];
            wb[u] = t.x; vb[u] = h2b[(size_t)__float_as_int(t.y) * 64 + lane];
        }
        #pragma unroll
        for (int u = 0; u < 8; ++u) {
            ax += wa[u] * __uint_as_float(va[u] << 16);
            ay += wa[u] * __uint_as_float(va[u] & 0xffff0000u);
        }
        #pragma unroll
        for (int u = 0; u < 8; ++u) { wa[u] = wb[u]; va[u] = vb[u]; }
    }
    #pragma unroll
    for (int u = 0; u < 8; ++u) {
        ax += wa[u] * __uint_as_float(va[u] << 16);
        ay += wa[u] * __uint_as_float(va[u] & 0xffff0000u);
    }

    for (int j = r0 + CAP; j < r1; ++j) {
        int s = esrc[j];
        float c = dinv[s];
        unsigned int v = h2b[(size_t)s * 64 + lane];
        ax += c * __uint_as_float(v << 16);
        ay += c * __uint_as_float(v & 0xffff0000u);
    }
    int g = batch[node];
    if (g < 0 || g >= NG) return;
    int p = node - gstart[g];
    if (p < 0 || p >= TT) return;
    float2 bv = *(const float2*)(bias + 2 * lane);
    float vx = fmaxf(ax * dn + bv.x, 0.f);
    float vy = fmaxf(ay * dn + bv.y, 0.f);
    size_t row = (size_t)g * TT + p;
    if (ph) {
        unsigned short hx = f2bf(vx), hy = f2bf(vy);
        *(ushort2*)(ph + row * DD + 2 * lane) = make_ushort2(hx, hy);
        *(ushort2*)(pl + row * DD + 2 * lane) =
            make_ushort2(f2bf(vx - bf2f(hx)), f2bf(vy - bf2f(hy)));
    } else {
        *(float2*)(padded + row * DD + 2 * lane) = make_float2(vx, vy);
    }
}

// ------------------------- LSTM (512 thr, 4-way split-K; 192us floor) ----------
// r19 configuration restored exactly (r20's launch_bounds(512,2)+asm keep-alive
// regressed to 208us: allocator perturbation, theory falsified).
__global__ __launch_bounds__(512) void k_lstm(
    const float* __restrict__ xw, const float* __restrict__ Whh,
    const int* __restrict__ gstart,
    float* __restrict__ hstate, float* __restrict__ cstate,
    float* __restrict__ grep, int t0, int clen)
{
    int g = blockIdx.x, tid = threadIdx.x;
    __shared__ __align__(16) float h_sh[DD];
    __shared__ __align__(16) float part[4][4 * PSTRIDE];

    const int seg = tid >> 7;
    const int gq  = tid & 127;
    const int qt  = gq >> 5;
    const int ub  = (gq & 31) * 4;
    const int u   = tid >> 2;
    const int q   = tid & 3;
    const int lane = tid & 63;
    const int qbase = lane & ~3;

    float4 w[4][8];
    #pragma unroll
    for (int g4 = 0; g4 < 4; ++g4)
        #pragma unroll
        for (int i = 0; i < 8; ++i)
            w[g4][i] = *(const float4*)(Whh + (size_t)(4 * gq + g4) * DD + seg * 32 + i * 4);

    float creg = 0.f, hn = 0.f;
    if (t0 == 0) {
        if (tid < DD) h_sh[tid] = 0.f;
    } else {
        creg = cstate[g * DD + u];
        hn = hstate[g * DD + u];
        if (q == 0) h_sh[u] = hn;
    }
    int take = gstart[g + 1] - gstart[g] - 1;
    if (take < 0) take = 0;
    if (take > TT - 1) take = TT - 1;
    __syncthreads();

    const float* xb = xw + (size_t)g * clen * GH + q * DD + u;
    float xv = xb[0];

    for (int t = t0; t < t0 + clen; ++t) {
        int rel = t - t0;
        float xvn = 0.f;
        if (rel + 1 < clen) xvn = xb[(size_t)(rel + 1) * GH];

        float4 hseg[8];
        #pragma unroll
        for (int i = 0; i < 8; ++i) hseg[i] = *(const float4*)(h_sh + seg * 32 + i * 4);
        float p0 = 0.f, p1 = 0.f, p2 = 0.f, p3 = 0.f;
        #pragma unroll
        for (int i = 0; i < 8; ++i) {
            float4 h4 = hseg[i];
            p0 += h4.x * w[0][i].x + h4.y * w[0][i].y + h4.z * w[0][i].z + h4.w * w[0][i].w;
            p1 += h4.x * w[1][i].x + h4.y * w[1][i].y + h4.z * w[1][i].z + h4.w * w[1][i].w;
            p2 += h4.x * w[2][i].x + h4.y * w[2][i].y + h4.z * w[2][i].z + h4.w * w[2][i].w;
            p3 += h4.x * w[3][i].x + h4.y * w[3][i].y + h4.z * w[3][i].z + h4.w * w[3][i].w;
        }
        *(float4*)(&part[seg][qt * PSTRIDE + ub]) = make_float4(p0, p1, p2, p3);
        __syncthreads();

        int pidx = q * PSTRIDE + u;
        float G = xv + part[0][pidx] + part[1][pidx] + part[2][pidx] + part[3][pidx];
        float a = (q == 2) ? 2.f : -1.f;
        float e = __expf(a * G);
        float act = (q == 2) ? (1.f - 2.f / (e + 1.f)) : (1.f / (1.f + e));
        float ai = __shfl(act, qbase + 0);
        float af = __shfl(act, qbase + 1);
        float ag = __shfl(act, qbase + 2);
        float ao = __shfl(act, qbase + 3);
        creg = af * creg + ai * ag;
        hn = ao * ftanh(creg);
        if (q == 0) {
            h_sh[u] = hn;
            if (t == take) grep[g * DD + u] = hn;
        }
        xv = xvn;
        __syncthreads();
    }
    if (q == 0) { hstate[g * DD + u] = hn; cstate[g * DD + u] = creg; }
}

// ------------------------- FC -------------------------
__global__ void k_fc(const float* __restrict__ grep, const float* __restrict__ Wfc,
                     const float* __restrict__ bfc, float* __restrict__ out, int G) {
    int i = blockIdx.x * 256 + threadIdx.x;
    if (i >= G * 2) return;
    int g = i >> 1, o = i & 1;
    float acc = bfc[o];
    for (int d = 0; d < DD; ++d) acc += grep[g * DD + d] * Wfc[d * 2 + o];
    out[i] = acc;
}

// ------------------------- host launch -------------------------
extern "C" void kernel_launch(void* const* d_in, const int* in_sizes, int n_in,
                              void* d_out, int out_size, void* d_ws, size_t ws_size,
                              hipStream_t stream) {
    const float* x     = (const float*)d_in[0];
    const int*   ei    = (const int*)d_in[1];
    const int*   batch = (const int*)d_in[2];
    const float* Wgat  = (const float*)d_in[3];
    const float* a_src = (const float*)d_in[4];
    const float* a_dst = (const float*)d_in[5];
    const float* b_gat = (const float*)d_in[6];
    const float* Wgcn  = (const float*)d_in[7];
    const float* b_gcn = (const float*)d_in[8];
    const float* Wih   = (const float*)d_in[9];   // [512,128]
    const float* Whh   = (const float*)d_in[10];  // [512,128]
    const float* b_ih  = (const float*)d_in[11];
    const float* b_hh  = (const float*)d_in[12];
    const float* Wfc   = (const float*)d_in[13];
    const float* b_fc  = (const float*)d_in[14];
    float* out = (float*)d_out;

    float* ws = (float*)d_ws;
    const size_t F = (size_t)NN * DD;  // 6.4M elements
    unsigned short* h1b = (unsigned short*)ws;
    unsigned short* h2b = (unsigned short*)ws;
    float* xwChunk = ws;
    float* gato   = ws + F;
    float* padded = ws + F;
    unsigned short* gato_hi = (unsigned short*)(ws + F);
    unsigned short* gato_lo = gato_hi + F;
    unsigned short* padded_hi = (unsigned short*)(ws + F);
    unsigned short* padded_lo = padded_hi + F;
    size_t off = 2 * F;
    float* alpha_s = ws + off; off += 50048;
    float* alpha_d = ws + off; off += 50048;
    float* dinv    = ws + off; off += 50048;
    int*   cnt     = (int*)(ws + off); off += 50048;
    int*   rp      = (int*)(ws + off); off += 50056;
    int*   fill    = (int*)(ws + off); off += 50048;
    int*   esrc    = (int*)(ws + off); off += 850048;
    int*   bsum    = (int*)(ws + off); off += 256;
    int*   gstart  = (int*)(ws + off); off += 256;
    float* grep    = ws + off; off += 32000;
    float* hstate  = ws + off; off += 32000;
    float* cstate  = ws + off; off += 32000;
    float* WgatT   = ws + off; off += 16384;
    float* WgcnT   = ws + off; off += 16384;
    unsigned short* wih_hi = (unsigned short*)(ws + off); off += 32768;
    unsigned short* wih_lo = (unsigned short*)(ws + off); off += 32768;
    unsigned short* wgatT_hi = (unsigned short*)(ws + off); off += 8192;
    unsigned short* wgatT_lo = (unsigned short*)(ws + off); off += 8192;
    unsigned short* wgcnT_hi = (unsigned short*)(ws + off); off += 8192;
    unsigned short* wgcnT_lo = (unsigned short*)(ws + off); off += 8192;
    unsigned short* x_hi = (unsigned short*)(ws + off); off += F / 2;
    unsigned short* x_lo = (unsigned short*)(ws + off); off += F / 2;
    const size_t xwBigFloats = (size_t)NG * TT * GH;   // 25.6M floats
    float* xwBig = ws + off;
    const bool big = ws_size >= (off + xwBigFloats) * sizeof(float);

    // 1. prep: transposes + all weight hi/lo splits
    k_prep<<<256, 256, 0, stream>>>(Wgat, WgatT, wgatT_hi, wgatT_lo,
                                    Wgcn, WgcnT, wgcnT_hi, wgcnT_lo,
                                    Wih, wih_hi, wih_lo);

    // 2. h1b = bf16(x @ W_gat), alpha fused
    if (big) {
        k_splitx<<<25000, 256, 0, stream>>>(x, x_hi, x_lo, (int)F);
        k_gemm_mx128<<<391, 256, 0, stream>>>(x_hi, x_lo, wgatT_hi, wgatT_lo, h1b, NN,
                                              alpha_s, alpha_d, a_src, a_dst);
    } else {
        k_gemm<<<dim3(391, 1), 256, 0, stream>>>(x, WgatT, nullptr, NN, DD, 0, TT, TT,
                                                 nullptr, nullptr, h1b,
                                                 alpha_s, alpha_d, a_src, a_dst);
    }

    // 3. CSR build
    k_init<<<196, 256, 0, stream>>>(cnt, gstart, NN, NG + 1);
    k_hist<<<3125, 256, 0, stream>>>(ei, cnt, NE);
    k_scan1<<<196, 256, 0, stream>>>(cnt, fill, bsum, NN);
    k_scan2<<<1, 256, 0, stream>>>(bsum, 196);
    k_scan3<<<196, 256, 0, stream>>>(bsum, cnt, rp, fill, dinv, batch, gstart, NN);
    k_fill<<<3321, 256, 0, stream>>>(ei, fill, esrc, NE, NN);

    // 4. GAT aggregation -> gato (hi/lo when big)
    if (big) {
        k_gat<<<12500, 256, 0, stream>>>((const unsigned int*)h1b, alpha_s, alpha_d,
                                         rp, esrc, b_gat, nullptr, gato_hi, gato_lo, NN);
    } else {
        k_gat<<<12500, 256, 0, stream>>>((const unsigned int*)h1b, alpha_s, alpha_d,
                                         rp, esrc, b_gat, gato, nullptr, nullptr, NN);
    }

    // 5. h2b = bf16(gato @ W_gcn)
    if (big) {
        k_gemm_mx128<<<391, 256, 0, stream>>>(gato_hi, gato_lo, wgcnT_hi, wgcnT_lo, h2b, NN,
                                              nullptr, nullptr, nullptr, nullptr);
    } else {
        k_gemm<<<dim3(391, 1), 256, 0, stream>>>(gato, WgcnT, nullptr, NN, DD, 0, TT, TT,
                                                 nullptr, nullptr, h2b,
                                                 nullptr, nullptr, nullptr, nullptr);
    }

    // 6. GCN aggregation -> padded (hi/lo when big)
    if (big) {
        k_gcn<<<12500, 256, 0, stream>>>((const unsigned int*)h2b, dinv, rp, esrc,
                                         b_gcn, batch, gstart, nullptr,
                                         padded_hi, padded_lo, NN);
    } else {
        k_gcn<<<12500, 256, 0, stream>>>((const unsigned int*)h2b, dinv, rp, esrc,
                                         b_gcn, batch, gstart, padded,
                                         nullptr, nullptr, NN);
    }

    // 7. LSTM: conversion-free MFMA xw gemm + 512-thread recurrence
    if (big) {
        k_gemm_mx<<<dim3(GRIDM, 4), 256, 0, stream>>>(padded_hi, padded_lo,
                                                      wih_hi, wih_lo,
                                                      xwBig, NG * TT, b_ih, b_hh);
        k_lstm<<<NG, 512, 0, stream>>>(xwBig, Whh, gstart, hstate, cstate, grep, 0, TT);
    } else {
        for (int c = 0; c < NCHUNK; ++c) {
            int t0 = c * CLEN;
            k_gemm<<<dim3(98, 4), 256, 0, stream>>>(padded, Wih, xwChunk, NG * CLEN, GH,
                                                    t0, CLEN, TT, b_ih, b_hh,
                                                    nullptr, nullptr, nullptr, nullptr, nullptr);
            k_lstm<<<NG, 512, 0, stream>>>(xwChunk, Whh, gstart, hstate, cstate, grep, t0, CLEN);
        }
    }

    // 8. FC
    k_fc<<<2, 256, 0, stream>>>(grep, Wfc, b_fc, out, NG);
}